// Round 3
// baseline (337.425 us; speedup 1.0000x reference)
//
#include <hip/hip_runtime.h>

#define T_STEPS 1024
#define B_DIM   128
#define D_DIM   256
#define H_DIM   256
#define DH      512   // D + H
#define INV2PI  0.15915494309189535f

// sigmoid(q) for |q|<=1 (q = sin(...)): Taylor deg-5, err <= 2.2e-4. FMA-only.
__device__ __forceinline__ float sig_poly(float q) {
    float t = q * q;
    float p = fmaf(t, 1.0f / 480.0f, -1.0f / 48.0f);
    p = fmaf(t, p, 0.25f);
    return fmaf(q, p, 0.5f);
}

// tanh(x) Pade(5,4): x(x^4+105x^2+945)/(15x^4+420x^2+945); err<1e-4 for |x|<=2.3.
// |c| provably <= 2.08 (fixed point of f*c+i*g with f,i<=0.731, g<=0.762).
__device__ __forceinline__ float tanh_pade(float x) {
    float t = x * x;
    float n = fmaf(t, t + 105.0f, 945.0f);
    float d = fmaf(t, fmaf(t, 15.0f, 420.0f), 945.0f);
    return x * n * __builtin_amdgcn_rcpf(d);
}

// xdot[row][k] = (x[row,:] . W[k,:256] + b[k]) * 1/(2*pi)  — pre-scaled to
// revolutions so k_scan can feed v_sin_f32 directly. Wave per row, grid-stride.
// Reduction: transpose-reduce (7 shuffles/row) instead of 4 independent
// 64-lane butterflies (24 shuffles/row):
//   stage 1 (xor 1): pair-sum p0/p1 by bit0, p2/p3 by bit0   (2 shfl)
//   stage 2 (xor 2): select A/B by bit1 -> lane L&3 owns gate L&3 (1 shfl)
//   stage 3: butterfly xor 4..32 over remaining 16 groups    (4 shfl)
// Lanes 0..3 store 4 scalars -> single 16B transaction.
__global__ __launch_bounds__(256) void k_xdot(const float* __restrict__ x,
                                              const float* __restrict__ W,
                                              const float* __restrict__ bias,
                                              float* __restrict__ xdot) {
    const int lane = threadIdx.x & 63;
    const int wid = blockIdx.x * (blockDim.x >> 6) + (threadIdx.x >> 6);
    const int nw = (gridDim.x * blockDim.x) >> 6;
    const int nrows = T_STEPS * B_DIM;

    float4 wk0 = ((const float4*)(W + 0 * DH))[lane];
    float4 wk1 = ((const float4*)(W + 1 * DH))[lane];
    float4 wk2 = ((const float4*)(W + 2 * DH))[lane];
    float4 wk3 = ((const float4*)(W + 3 * DH))[lane];
    const float bl = bias[lane & 3];   // bias for the gate this lane will own

    const float4* xv4 = (const float4*)x;  // 64 float4 per row

    const bool b0 = (lane & 1) != 0;
    const bool b1 = (lane & 2) != 0;

    int row = wid;
    if (row >= nrows) return;
    float4 xv = xv4[row * 64 + lane];
    for (; row < nrows; row += nw) {
        float4 cur = xv;
        int nrow = row + nw;
        if (nrow < nrows) xv = xv4[nrow * 64 + lane];  // prefetch next row

        float p0 = fmaf(cur.x, wk0.x, fmaf(cur.y, wk0.y, fmaf(cur.z, wk0.z, cur.w * wk0.w)));
        float p1 = fmaf(cur.x, wk1.x, fmaf(cur.y, wk1.y, fmaf(cur.z, wk1.z, cur.w * wk1.w)));
        float p2 = fmaf(cur.x, wk2.x, fmaf(cur.y, wk2.y, fmaf(cur.z, wk2.z, cur.w * wk2.w)));
        float p3 = fmaf(cur.x, wk3.x, fmaf(cur.y, wk3.y, fmaf(cur.z, wk3.w, cur.w * wk3.w)));
        // NOTE: p3 inner term fixed below (cur.z * wk3.z) — see corrected line.
        p3 = fmaf(cur.x, wk3.x, fmaf(cur.y, wk3.y, fmaf(cur.z, wk3.z, cur.w * wk3.w)));

        // stage 1: exchange across xor 1
        float sA = b0 ? p0 : p1;
        sA = __shfl_xor(sA, 1, 64);
        float A = (b0 ? p1 : p0) + sA;      // pair-sum of p_{bit0}
        float sB = b0 ? p2 : p3;
        sB = __shfl_xor(sB, 1, 64);
        float B = (b0 ? p3 : p2) + sB;      // pair-sum of p_{2+bit0}
        // stage 2: exchange across xor 2
        float s2 = b1 ? A : B;
        s2 = __shfl_xor(s2, 2, 64);
        float v = (b1 ? B : A) + s2;        // 4-lane-group sum of p_{lane&3}
        // stage 3: butterfly over the 16 groups
#pragma unroll
        for (int off = 4; off < 64; off <<= 1) v += __shfl_xor(v, off, 64);

        if (lane < 4) xdot[row * 4 + lane] = (v + bl) * INV2PI;
    }
}

// sequential scan: 128 independent chains. Prefetch ring kept in REGISTERS:
// inner loop fully unrolled with constant indices so SROA promotes buf[].
// __launch_bounds__(128, 1): 1 wave/EU min -> ~512 VGPR budget. Without this
// the allocator capped at 52 VGPRs (8-wave occupancy heuristic), buf[16]
// (64 VGPRs) could not stay live, and the compiler sank every prefetch load
// to its use point -> one exposed L2/IF$ latency (~200 cy) per step
// (measured 244 cy/step, VALUBusy 36% of the active CU).
// hseq layout: [b][t] (thread-major) so each thread stores one float4 per
// 4 steps instead of four scalar stores.
// NOTE: prefetch reads up to 16 rows past T_STEPS*B_DIM — caller guarantees
// xdot has >= (T_STEPS+16)*B_DIM float4 of backing store (it's in d_out).
__global__ __launch_bounds__(128, 1) void k_scan(const float* __restrict__ xdot,
                                                 const float* __restrict__ W,
                                                 float* __restrict__ hseq,
                                                 float* __restrict__ cfin) {
    const int b = threadIdx.x;  // 0..127
    __shared__ float s_whp[4];
    {   // whp[k] = (sum_h W[k, 256+h]) * 1/(2*pi); threads (k = b>>5, j = b&31)
        int k = b >> 5, j = b & 31;
        const float4* wr = (const float4*)(W + k * DH + D_DIM + j * 8);
        float4 v0 = wr[0], v1 = wr[1];
        float s = (v0.x + v0.y) + (v0.z + v0.w) + (v1.x + v1.y) + (v1.z + v1.w);
#pragma unroll
        for (int off = 16; off > 0; off >>= 1) s += __shfl_xor(s, off, 32);
        if (j == 0) s_whp[k] = s * INV2PI;   // REVOLUTIONS: must match xdot scaling
    }
    __syncthreads();
    const float w0 = s_whp[0], w1 = s_whp[1], w2 = s_whp[2], w3 = s_whp[3];
    const float4* xr = (const float4*)xdot;  // [t*128 + b]

    float4 buf[16];
#pragma unroll
    for (int p = 0; p < 16; ++p) buf[p] = xr[p * B_DIM + b];

    float c = 0.0f, h = 0.0f;
    float4* hout4 = (float4*)(hseq + b * T_STEPS);  // per-thread contiguous row
    float4 h4;
    for (int tb = 0; tb < T_STEPS; tb += 16) {
#pragma unroll
        for (int j = 0; j < 16; ++j) {          // j is compile-time constant
            float4 cur = buf[j];
            buf[j] = xr[(tb + 16 + j) * B_DIM + b];   // 16 steps ahead (padded)

            // args already in revolutions: sin(lin) == v_sin(lin/(2*pi))
            float q0 = __builtin_amdgcn_sinf(fmaf(h, w0, cur.x));
            float q1 = __builtin_amdgcn_sinf(fmaf(h, w1, cur.y));
            float q2 = __builtin_amdgcn_sinf(fmaf(h, w2, cur.z));
            float q3 = __builtin_amdgcn_sinf(fmaf(h, w3, cur.w));
            float f = sig_poly(q0);
            float i = sig_poly(q1);
            float g = tanh_pade(q2);
            float o = sig_poly(q3);
            c = fmaf(f, c, i * g);
            h = o * tanh_pade(c);
            if ((j & 3) == 0)      h4.x = h;
            else if ((j & 3) == 1) h4.y = h;
            else if ((j & 3) == 2) h4.z = h;
            else { h4.w = h; hout4[(tb + j) >> 2] = h4; }
        }
    }
    cfin[b] = c;
}

// broadcast h over H=256 columns; wave per output row of 64 float4s.
// rows: [0,131072) stacked, [131072,131200) hx, [131200,131328) cx
// hseq is [b][t]-major: value for output row r=(t*128+b) is hseq[b*1024 + t].
__global__ __launch_bounds__(256) void k_bcast(const float* __restrict__ hseq,
                                               const float* __restrict__ cfin,
                                               float4* __restrict__ out) {
    const int wave = blockIdx.x * (blockDim.x >> 6) + (threadIdx.x >> 6);
    const int lane = threadIdx.x & 63;
    const int NR = T_STEPS * B_DIM;
    if (wave >= NR + 2 * B_DIM) return;
    float v;
    if (wave < NR) {
        int t = wave >> 7, bb = wave & 127;
        v = hseq[bb * T_STEPS + t];
    } else if (wave < NR + B_DIM) {
        v = hseq[(wave - NR) * T_STEPS + (T_STEPS - 1)];
    } else {
        v = cfin[wave - NR - B_DIM];
    }
    out[(size_t)wave * 64 + lane] = make_float4(v, v, v, v);
}

extern "C" void kernel_launch(void* const* d_in, const int* in_sizes, int n_in,
                              void* d_out, int out_size, void* d_ws, size_t ws_size,
                              hipStream_t stream) {
    const float* x = (const float*)d_in[0];   // (1024,128,256) f32
    const float* W = (const float*)d_in[1];   // (4,512) f32
    const float* b = (const float*)d_in[2];   // (4,) f32
    // d_in[3] = qw — mathematically inert (sin invariant under RX then H)

    float* out = (float*)d_out;

    float* wsf  = (float*)d_ws;
    float* hseq = wsf + 16;                      // 131072 floats, [b][t]
    float* cfin = wsf + 16 + T_STEPS * B_DIM;    // 128 floats
    float* xdot = out;  // 8.5 MB scratch in d_out head (incl. 16-row pad);
                        // d_out is 134 MB and fully overwritten by k_bcast.

    k_xdot<<<2048, 256, 0, stream>>>(x, W, b, xdot);
    k_scan<<<1, 128, 0, stream>>>(xdot, W, hseq, cfin);

    const int rows = T_STEPS * B_DIM + 2 * B_DIM;          // 131328
    k_bcast<<<(rows + 3) / 4, 256, 0, stream>>>(hseq, cfin, (float4*)out);
}

// Round 4
// 304.908 us; speedup vs baseline: 1.1066x; 1.1066x over previous
//
#include <hip/hip_runtime.h>

#define T_STEPS 1024
#define B_DIM   128
#define D_DIM   256
#define H_DIM   256
#define DH      512   // D + H
#define INV2PI  0.15915494309189535f

// tanh(x) Pade(5,4): x(x^4+105x^2+945)/(15x^4+420x^2+945); err<1e-4 for |x|<=2.3.
// |c| provably <= 2.08 (fixed point of f*c+i*g with f,i<=0.731, g<=0.762).
__device__ __forceinline__ float tanh_pade(float x) {
    float t = x * x;
    float n = fmaf(t, t + 105.0f, 945.0f);
    float d = fmaf(t, fmaf(t, 15.0f, 420.0f), 945.0f);
    return x * n * __builtin_amdgcn_rcpf(d);
}

// quad_perm broadcast of role K within each 4-lane group (VALU DPP, no LDS).
template <int K>
__device__ __forceinline__ float quad_bcast(float v) {
    // dpp_ctrl quad_perm[K,K,K,K] = K * 0b01010101
    int r = __builtin_amdgcn_mov_dpp(__builtin_bit_cast(int, v), K * 0x55, 0xF, 0xF, true);
    return __builtin_bit_cast(float, r);
}

// xdot[row][k] = (x[row,:] . W[k,:256] + b[k]) * 1/(2*pi)  — pre-scaled to
// revolutions so k_scan can feed v_sin_f32 directly. Wave per row, grid-stride.
// Transpose-reduce: 7 shuffles/row instead of 24 (4 independent butterflies).
__global__ __launch_bounds__(256) void k_xdot(const float* __restrict__ x,
                                              const float* __restrict__ W,
                                              const float* __restrict__ bias,
                                              float* __restrict__ xdot) {
    const int lane = threadIdx.x & 63;
    const int wid = blockIdx.x * (blockDim.x >> 6) + (threadIdx.x >> 6);
    const int nw = (gridDim.x * blockDim.x) >> 6;
    const int nrows = T_STEPS * B_DIM;

    float4 wk0 = ((const float4*)(W + 0 * DH))[lane];
    float4 wk1 = ((const float4*)(W + 1 * DH))[lane];
    float4 wk2 = ((const float4*)(W + 2 * DH))[lane];
    float4 wk3 = ((const float4*)(W + 3 * DH))[lane];
    const float bl = bias[lane & 3];   // bias for the gate this lane will own

    const float4* xv4 = (const float4*)x;  // 64 float4 per row

    const bool b0 = (lane & 1) != 0;
    const bool b1 = (lane & 2) != 0;

    int row = wid;
    if (row >= nrows) return;
    float4 xv = xv4[row * 64 + lane];
    for (; row < nrows; row += nw) {
        float4 cur = xv;
        int nrow = row + nw;
        if (nrow < nrows) xv = xv4[nrow * 64 + lane];  // prefetch next row

        float p0 = fmaf(cur.x, wk0.x, fmaf(cur.y, wk0.y, fmaf(cur.z, wk0.z, cur.w * wk0.w)));
        float p1 = fmaf(cur.x, wk1.x, fmaf(cur.y, wk1.y, fmaf(cur.z, wk1.z, cur.w * wk1.w)));
        float p2 = fmaf(cur.x, wk2.x, fmaf(cur.y, wk2.y, fmaf(cur.z, wk2.z, cur.w * wk2.w)));
        float p3 = fmaf(cur.x, wk3.x, fmaf(cur.y, wk3.y, fmaf(cur.z, wk3.z, cur.w * wk3.w)));

        // stage 1: exchange across xor 1
        float sA = b0 ? p0 : p1;
        sA = __shfl_xor(sA, 1, 64);
        float A = (b0 ? p1 : p0) + sA;      // pair-sum of p_{bit0}
        float sB = b0 ? p2 : p3;
        sB = __shfl_xor(sB, 1, 64);
        float B = (b0 ? p3 : p2) + sB;      // pair-sum of p_{2+bit0}
        // stage 2: exchange across xor 2
        float s2 = b1 ? A : B;
        s2 = __shfl_xor(s2, 2, 64);
        float v = (b1 ? B : A) + s2;        // 4-lane-group sum of p_{lane&3}
        // stage 3: butterfly over the 16 groups
#pragma unroll
        for (int off = 4; off < 64; off <<= 1) v += __shfl_xor(v, off, 64);

        if (lane < 4) xdot[row * 4 + lane] = (v + bl) * INV2PI;
    }
}

// Sequential scan, 4 LANES PER CHAIN. 512 threads = 2 blocks x 256 = 8 waves,
// 1 wave/SIMD across 2 CUs. Lane r = tid&3 owns gate r of chain tid>>2:
//   r=0: f (sigmoid), r=1: i (sigmoid), r=2: g (tanh), r=3: o (sigmoid).
// Rationale (measured r1/r3): the 1-lane/chain version was ISSUE-bound
// (~176 busy cy/step on 2 SIMDs; 6 trans x ~16cy dominate). Splitting the 4
// sin+poly across 4 lanes cuts per-wave issue ~4x; gates are exchanged with
// 4 VALU DPP quad_perm broadcasts (no LDS). Gate nonlinearity is one odd
// Horner poly with per-lane coefficients (no divergence):
//   sigmoid: 0.5 + q(1/4 - t/48 + t^2/480 - 17 t^3/80640), t=q^2 (err ~2e-5)
//   tanh:    q(0.999904 - 0.331065 t + 0.120472 t^2 - 0.027717 t^3) (err ~1.5e-4)
// tanh(c) stays Pade (err <1e-4). amdgpu_waves_per_eu(1,1): pins the
// scheduler's occupancy target to 1 wave/EU so the 16-deep prefetch ring
// (16 VGPR) is not sunk to uses (r3: launch_bounds(128,1) alone did NOT
// prevent sinking; VGPR stayed 52).
__global__ __launch_bounds__(256)
__attribute__((amdgpu_waves_per_eu(1, 1)))
void k_scan(const float* __restrict__ xdot,
            const float* __restrict__ W,
            float* __restrict__ hseq,
            float* __restrict__ cfin) {
    const int tid = blockIdx.x * 256 + threadIdx.x;   // 0..511
    const int r = tid & 3;                            // gate role
    const int chain = tid >> 2;                       // 0..127

    __shared__ float s_whp[4];
    {   // whp[k] = sum_h W[k, 256+h]; redundantly computed by both 128-halves
        int k = (threadIdx.x >> 5) & 3, j = threadIdx.x & 31;
        const float4* wr = (const float4*)(W + k * DH + D_DIM + j * 8);
        float4 v0 = wr[0], v1 = wr[1];
        float s = (v0.x + v0.y) + (v0.z + v0.w) + (v1.x + v1.y) + (v1.z + v1.w);
#pragma unroll
        for (int off = 16; off > 0; off >>= 1) s += __shfl_xor(s, off, 32);
        if (j == 0) s_whp[k] = s;
    }
    __syncthreads();
    const float wl = s_whp[r] * INV2PI;   // REVOLUTIONS: matches xdot scaling

    const bool isg = (r == 2);
    const float B0 = isg ? 0.0f       : 0.5f;
    const float B1 = isg ? 0.999904f  : 0.25f;
    const float B3 = isg ? -0.331065f : -1.0f / 48.0f;
    const float B5 = isg ? 0.120472f  : 1.0f / 480.0f;
    const float B7 = isg ? -0.027717f : -17.0f / 80640.0f;

    // prefetch ring: one gate scalar per lane per step; xdot[t*512 + tid] is
    // perfectly coalesced (256B per wave per step).
    // NOTE: reads up to t=T_STEPS+15 — xdot backing store (d_out) has
    // >= (T_STEPS+16)*512 floats. Caller guarantees.
    float ring[16];
#pragma unroll
    for (int p = 0; p < 16; ++p) ring[p] = xdot[p * 512 + tid];

    float c = 0.0f, h = 0.0f;
    float4 h4;
    float4* hout4 = (float4*)(hseq + chain * T_STEPS);  // [b][t] layout
    for (int tb = 0; tb < T_STEPS; tb += 16) {
#pragma unroll
        for (int j = 0; j < 16; ++j) {          // j is compile-time constant
            float cur = ring[j];
            ring[j] = xdot[(tb + 16 + j) * 512 + tid];   // 16 steps ahead

            float sn = __builtin_amdgcn_sinf(fmaf(h, wl, cur));  // q_r = sin(lin_r)
            float t = sn * sn;
            float p = fmaf(t, B7, B5);
            p = fmaf(t, p, B3);
            p = fmaf(t, p, B1);
            float gate = fmaf(sn, p, B0);       // f/i/o: sigmoid(q); g: tanh(q)

            float fv = quad_bcast<0>(gate);
            float iv = quad_bcast<1>(gate);
            float gv = quad_bcast<2>(gate);
            float ov = quad_bcast<3>(gate);

            c = fmaf(fv, c, iv * gv);
            h = ov * tanh_pade(c);              // redundant in 4 lanes; uniform

            if ((j & 3) == 0)      h4.x = h;
            else if ((j & 3) == 1) h4.y = h;
            else if ((j & 3) == 2) h4.z = h;
            else { h4.w = h; if (r == 0) hout4[(tb + j) >> 2] = h4; }
        }
    }
    if (r == 0) cfin[chain] = c;
}

// broadcast h over H=256 columns; wave per output row of 64 float4s.
// rows: [0,131072) stacked, [131072,131200) hx, [131200,131328) cx
// hseq is [b][t]-major: value for output row r=(t*128+b) is hseq[b*1024 + t].
__global__ __launch_bounds__(256) void k_bcast(const float* __restrict__ hseq,
                                               const float* __restrict__ cfin,
                                               float4* __restrict__ out) {
    const int wave = blockIdx.x * (blockDim.x >> 6) + (threadIdx.x >> 6);
    const int lane = threadIdx.x & 63;
    const int NR = T_STEPS * B_DIM;
    if (wave >= NR + 2 * B_DIM) return;
    float v;
    if (wave < NR) {
        int t = wave >> 7, bb = wave & 127;
        v = hseq[bb * T_STEPS + t];
    } else if (wave < NR + B_DIM) {
        v = hseq[(wave - NR) * T_STEPS + (T_STEPS - 1)];
    } else {
        v = cfin[wave - NR - B_DIM];
    }
    out[(size_t)wave * 64 + lane] = make_float4(v, v, v, v);
}

extern "C" void kernel_launch(void* const* d_in, const int* in_sizes, int n_in,
                              void* d_out, int out_size, void* d_ws, size_t ws_size,
                              hipStream_t stream) {
    const float* x = (const float*)d_in[0];   // (1024,128,256) f32
    const float* W = (const float*)d_in[1];   // (4,512) f32
    const float* b = (const float*)d_in[2];   // (4,) f32
    // d_in[3] = qw — mathematically inert (sin invariant under RX then H)

    float* out = (float*)d_out;

    float* wsf  = (float*)d_ws;
    float* hseq = wsf + 16;                      // 131072 floats, [b][t]
    float* cfin = wsf + 16 + T_STEPS * B_DIM;    // 128 floats
    float* xdot = out;  // 8.5 MB scratch in d_out head (incl. 16-row pad);
                        // d_out is 134 MB and fully overwritten by k_bcast.

    k_xdot<<<2048, 256, 0, stream>>>(x, W, b, xdot);
    k_scan<<<2, 256, 0, stream>>>(xdot, W, hseq, cfin);

    const int rows = T_STEPS * B_DIM + 2 * B_DIM;          // 131328
    k_bcast<<<(rows + 3) / 4, 256, 0, stream>>>(hseq, cfin, (float4*)out);
}